// Round 13
// baseline (163.337 us; speedup 1.0000x reference)
//
#include <hip/hip_runtime.h>
#include <hip/hip_bf16.h>

#define NB 4
#define NC 512
#define NN 4096
#define NM 640
#define IB 64            // i-block per iteration
#define NT (NN / IB)     // 64 iterations
#define LOG2E 1.4426950408889634f

typedef __attribute__((ext_vector_type(8))) short bf16x8;
typedef __attribute__((ext_vector_type(4))) float f32x4;

__device__ __forceinline__ f32x4 mfma16(bf16x8 a, bf16x8 b, f32x4 c) {
  return __builtin_amdgcn_mfma_f32_16x16x32_bf16(a, b, c, 0, 0, 0);
}

__device__ __forceinline__ unsigned short f2bf(float f) {
  unsigned int u = __float_as_uint(f);
  u += 0x7fffu + ((u >> 16) & 1u);   // round-to-nearest-even
  return (unsigned short)(u >> 16);
}

typedef const __attribute__((address_space(1))) char gchar_t;
typedef __attribute__((address_space(3))) char lchar_t;

// ---------------- pack weights: W[640][512] bf16 + bias[640] f32 ----------------
__global__ void pack_w(const float* __restrict__ wq, const float* __restrict__ bq,
                       const float* __restrict__ wk, const float* __restrict__ bk,
                       const float* __restrict__ wv, const float* __restrict__ bv,
                       unsigned short* __restrict__ W, float* __restrict__ bias) {
  int idx = blockIdx.x * 256 + threadIdx.x;
  if (idx < NM * NC) {
    int r = idx >> 9, c = idx & (NC - 1);
    float v;
    if (r < 64) v = wq[r * NC + c];
    else if (r < 128) v = wk[(r - 64) * NC + c];
    else v = wv[(r - 128) * NC + c];
    W[idx] = f2bf(v);
  }
  if (idx < NM)
    bias[idx] = (idx < 64) ? bq[idx] : (idx < 128 ? bk[idx - 64] : bv[idx - 128]);
}

// ---------------- transpose + convert: x[b][c][n] f32 -> XT[b][n][c] bf16 ----------------
__global__ void xpose(const float* __restrict__ x, unsigned short* __restrict__ XT) {
  __shared__ float t[64][65];
  int b = blockIdx.z;
  int c0 = blockIdx.y * 64, n0 = blockIdx.x * 64;
  int tx = threadIdx.x & 63, ty = threadIdx.x >> 6;  // 256 threads
  const float* xb = x + (size_t)b * NC * NN;
#pragma unroll
  for (int i = 0; i < 16; ++i) {
    int c = i * 4 + ty;
    t[c][tx] = xb[(size_t)(c0 + c) * NN + n0 + tx];
  }
  __syncthreads();
  unsigned short* xtb = XT + (size_t)b * NN * NC;
#pragma unroll
  for (int i = 0; i < 16; ++i) {
    int n = i * 4 + ty;
    xtb[(size_t)(n0 + n) * NC + c0 + tx] = f2bf(t[tx][n]);
  }
}

// ---------------- QKV projection GEMM (NT): C[m][n] = sum_k W[m][k]*XT[n][k] ----------------
__global__ __launch_bounds__(512) void gemm_qkv(
    const unsigned short* __restrict__ W, const float* __restrict__ bias,
    const unsigned short* __restrict__ XT,
    unsigned short* __restrict__ QT, unsigned short* __restrict__ KT,
    unsigned short* __restrict__ V) {
  int b = blockIdx.z;
  int m0 = blockIdx.y * 80;
  int wave = threadIdx.x >> 6, lane = threadIdx.x & 63;
  int nw = blockIdx.x * 512 + wave * 64;
  int lcol = lane & 15, lkg = lane >> 4;
  const unsigned short* xtb = XT + (size_t)b * NN * NC;
  f32x4 acc[5][4] = {};
  for (int k0 = 0; k0 < NC; k0 += 32) {
    int ko = k0 + lkg * 8;
    bf16x8 afr[5], bfr[4];
#pragma unroll
    for (int i = 0; i < 5; ++i)
      afr[i] = *reinterpret_cast<const bf16x8*>(W + (size_t)(m0 + 16 * i + lcol) * NC + ko);
#pragma unroll
    for (int j = 0; j < 4; ++j)
      bfr[j] = *reinterpret_cast<const bf16x8*>(xtb + (size_t)(nw + 16 * j + lcol) * NC + ko);
#pragma unroll
    for (int i = 0; i < 5; ++i)
#pragma unroll
      for (int j = 0; j < 4; ++j)
        acc[i][j] = mfma16(afr[i], bfr[j], acc[i][j]);
  }
  int rbase = lkg * 4;
#pragma unroll
  for (int i = 0; i < 5; ++i) {
    int mrow = m0 + 16 * i;
    if (mrow < 128) {
      bool isq = mrow < 64;
      unsigned short* T = isq ? (QT + (size_t)b * NN * 64) : (KT + (size_t)b * NN * 64);
      int mb = mrow & 63;
      float sc = isq ? LOG2E : 1.0f;
#pragma unroll
      for (int j = 0; j < 4; ++j) {
        int n = nw + 16 * j + lcol;
        union { unsigned short h[4]; unsigned long long u; } pk;
#pragma unroll
        for (int r = 0; r < 4; ++r)
          pk.h[r] = f2bf((acc[i][j][r] + bias[mrow + rbase + r]) * sc);
        *reinterpret_cast<unsigned long long*>(T + (size_t)n * 64 + mb + rbase) = pk.u;
      }
    } else {
      unsigned short* vb = V + (size_t)b * NC * NN;
#pragma unroll
      for (int r = 0; r < 4; ++r) {
        int m = mrow + rbase + r;
        float bs = bias[m];
        int c = m - 128;
#pragma unroll
        for (int j = 0; j < 4; ++j) {
          int n = nw + 16 * j + lcol;
          vb[(size_t)c * NN + n] = f2bf(acc[i][j][r] + bs);
        }
      }
    }
  }
}

// ---------------- fused attention PV: 16 waves (4/SIMD), R12 layouts ----------------
// grid 256 = (b XCD-pair, jb), 1024 threads. Wave w: QK^T tile (sw=w&3, fq=w>>2),
// owns c rows [32w, 32w+32) for PV/epilogue, stages those rows' V via global_load_lds.
// Per-wave chain halves vs R12; 4 waves/SIMD hide each other's stalls (softmax VALU
// of one wave overlaps PV MFMA of another). No max subtraction; L in-kernel.
__global__ __launch_bounds__(1024, 4) void attn_pv(
    const unsigned short* __restrict__ QT, const unsigned short* __restrict__ KT,
    const unsigned short* __restrict__ V, const float* __restrict__ x,
    const float* __restrict__ gamma, float* __restrict__ out) {
  int bid = blockIdx.x;
  int b = (bid & 7) >> 1;
  int jb = ((bid >> 3) << 1) | (bid & 1);
  int j0 = jb * 64;
  int wave = threadIdx.x >> 6, lane = threadIdx.x & 63;
  int lcol = lane & 15, lkg = lane >> 4;
  int sw = wave & 3;     // i-strip 0..3
  int fq = wave >> 2;    // fn for QK^T 0..3

  __shared__ __align__(16) unsigned short vlds[2][512 * IB];  // 128 KB, V dbuf
  __shared__ __align__(16) unsigned short plds[2][64 * IB];   //  16 KB, P^T dbuf
  __shared__ float sml[4][16][4];                             //   1 KB, L cross-wave

  const unsigned short* qt = QT + (size_t)b * NN * 64;
  const unsigned short* kt = KT + (size_t)b * NN * 64;
  const unsigned short* vp = V + (size_t)b * NC * NN;

  // staging geometry: lane -> (row within 8-row group, swizzled 16B unit)
  const int lrow = lane >> 3;                       // 0..7
  const int lswz = ((lane & 7) ^ lrow) << 3;        // source elem offset (unit ^ row&7)
  lchar_t* vbase = (lchar_t*)vlds;

  auto stage = [&](int itv) {
    int i0 = (itv & (NT - 1)) * IB;
    lchar_t* lb = vbase + (size_t)(itv & 1) * (512 * IB * 2) + wave * (32 * IB * 2);
#pragma unroll
    for (int q = 0; q < 4; ++q) {
      const unsigned short* gp = vp + (size_t)(wave * 32 + q * 8 + lrow) * NN + i0 + lswz;
      __builtin_amdgcn_global_load_lds((gchar_t*)gp, lb + q * 1024, 16, 0, 0);
    }
  };

  // K fragments for this wave's single fn = fq
  bf16x8 kfr[2];
#pragma unroll
  for (int ks = 0; ks < 2; ++ks)
    kfr[ks] = *reinterpret_cast<const bf16x8*>(
        kt + (size_t)(j0 + 16 * fq + lcol) * 64 + ks * 32 + lkg * 8);

  f32x4 oacc[2][4] = {};  // [cm][fn]; wave owns c rows [32w, 32w+32)
  float l_loc = 0.f;      // per-lane L partial for column j = 16fq + lcol

  // loop-invariant P-write byte offset
  const int jw = 16 * fq + lcol;
  const int pwoff = (jw * 128 + sw * 32 + lkg * 8) ^ ((jw & 7) << 4);

  // prologue: stage V(0), load Q(0)
  stage(0);
  bf16x8 qA[2], qB[2];
  {
    int row = sw * 16 + lcol;
    qA[0] = *reinterpret_cast<const bf16x8*>(qt + (size_t)row * 64 + lkg * 8);
    qA[1] = *reinterpret_cast<const bf16x8*>(qt + (size_t)row * 64 + 32 + lkg * 8);
  }

#define PV_ITER(IT, QC, QN)                                                       \
  {                                                                               \
    const int it_ = (IT);                                                         \
    stage(it_ + 1);                                                               \
    f32x4 s = {};                                                                 \
    s = mfma16(QC[0], kfr[0], s);                                                 \
    s = mfma16(QC[1], kfr[1], s);                                                 \
    {                                                                             \
      int row = ((it_ + 1) & (NT - 1)) * IB + sw * 16 + lcol;                     \
      QN[0] = *reinterpret_cast<const bf16x8*>(qt + (size_t)row * 64 + lkg * 8);  \
      QN[1] = *reinterpret_cast<const bf16x8*>(qt + (size_t)row * 64 + 32 + lkg * 8); \
    }                                                                             \
    char* pb = (char*)plds[it_ & 1];                                              \
    {                                                                             \
      float p0 = exp2f(s[0]), p1 = exp2f(s[1]);                                   \
      float p2 = exp2f(s[2]), p3 = exp2f(s[3]);                                   \
      l_loc += (p0 + p1) + (p2 + p3);                                             \
      union { unsigned short h[4]; unsigned long long u; } pk;                    \
      pk.h[0] = f2bf(p0); pk.h[1] = f2bf(p1);                                     \
      pk.h[2] = f2bf(p2); pk.h[3] = f2bf(p3);                                     \
      *reinterpret_cast<unsigned long long*>(pb + pwoff) = pk.u;                  \
    }                                                                             \
    asm volatile("s_waitcnt vmcnt(6) lgkmcnt(0)" ::: "memory");                   \
    __builtin_amdgcn_s_barrier();                                                 \
    asm volatile("" ::: "memory");                                                \
    const char* vb = (const char*)vlds[it_ & 1];                                  \
    __builtin_amdgcn_s_setprio(1);                                                \
    _Pragma("unroll") for (int ks = 0; ks < 2; ++ks) {                            \
      bf16x8 pfr[4];                                                              \
      _Pragma("unroll") for (int fn = 0; fn < 4; ++fn) {                          \
        int j = 16 * fn + lcol;                                                   \
        int bo = (j * 128 + ks * 64 + lkg * 16) ^ ((j & 7) << 4);                 \
        pfr[fn] = *reinterpret_cast<const bf16x8*>(pb + bo);                      \
      }                                                                           \
      _Pragma("unroll") for (int cm = 0; cm < 2; ++cm) {                          \
        int cr = 32 * wave + 16 * cm + lcol;                                      \
        int u = (ks * 4 + lkg) ^ (cr & 7);                                        \
        bf16x8 vfr = *reinterpret_cast<const bf16x8*>(vb + cr * 128 + u * 16);    \
        _Pragma("unroll") for (int fn = 0; fn < 4; ++fn)                          \
          oacc[cm][fn] = mfma16(vfr, pfr[fn], oacc[cm][fn]);                      \
      }                                                                           \
    }                                                                             \
    __builtin_amdgcn_s_setprio(0);                                                \
  }

  for (int it2 = 0; it2 < NT; it2 += 2) {
    PV_ITER(it2 + 0, qA, qB);
    PV_ITER(it2 + 1, qB, qA);
  }
#undef PV_ITER

  // ---- L cross-wave reduce: intra-wave over lkg replicas, then LDS over sw strips ----
  l_loc += __shfl_xor(l_loc, 16);
  l_loc += __shfl_xor(l_loc, 32);
  if (lane < 16) sml[fq][lane][sw] = l_loc;
  __syncthreads();
  float lj[4];
#pragma unroll
  for (int fn = 0; fn < 4; ++fn) {
    const float* p = sml[fn][lcol];
    lj[fn] = (p[0] + p[1]) + (p[2] + p[3]);
  }

  // ---- epilogue: out = gamma * O/l + x ----
  float g = gamma[0];
  const float* xb = x + (size_t)b * NC * NN;
  float* ob = out + (size_t)b * NC * NN;
#pragma unroll
  for (int fn = 0; fn < 4; ++fn) {
    float sc = g / lj[fn];
    int j = j0 + 16 * fn + lcol;
#pragma unroll
    for (int cm = 0; cm < 2; ++cm) {
      int c = 32 * wave + 16 * cm + lkg * 4;
#pragma unroll
      for (int r = 0; r < 4; ++r) {
        size_t idx = (size_t)(c + r) * NN + j;
        ob[idx] = oacc[cm][fn][r] * sc + xb[idx];
      }
    }
  }
}

extern "C" void kernel_launch(void* const* d_in, const int* in_sizes, int n_in,
                              void* d_out, int out_size, void* d_ws, size_t ws_size,
                              hipStream_t stream) {
  const float* x  = (const float*)d_in[0];
  const float* wq = (const float*)d_in[1];
  const float* bq = (const float*)d_in[2];
  const float* wk = (const float*)d_in[3];
  const float* bk = (const float*)d_in[4];
  const float* wv = (const float*)d_in[5];
  const float* bv = (const float*)d_in[6];
  const float* gm = (const float*)d_in[7];
  float* out = (float*)d_out;

  char* ws = (char*)d_ws;
  unsigned short* XT = (unsigned short*)(ws);                             // 16 MB
  unsigned short* Vb = (unsigned short*)(ws + (size_t)16 * 1024 * 1024);  // 16 MB
  unsigned short* QT = (unsigned short*)(ws + (size_t)32 * 1024 * 1024);  // 2 MB
  unsigned short* KT = (unsigned short*)(ws + (size_t)34 * 1024 * 1024);  // 2 MB
  unsigned short* Wp = (unsigned short*)(ws + (size_t)36 * 1024 * 1024);  // 640 KB
  float* biasp = (float*)(ws + (size_t)36 * 1024 * 1024 + 704 * 1024);    // 2.5 KB

  pack_w<<<(NM * NC + 255) / 256, 256, 0, stream>>>(wq, bq, wk, bk, wv, bv, Wp, biasp);
  xpose<<<dim3(NN / 64, NC / 64, NB), 256, 0, stream>>>(x, XT);
  gemm_qkv<<<dim3(NN / 512, NM / 80, NB), 512, 0, stream>>>(Wp, biasp, XT, QT, KT, Vb);
  attn_pv<<<256, 1024, 0, stream>>>(QT, KT, Vb, x, gm, out);
}

// Round 14
// 154.176 us; speedup vs baseline: 1.0594x; 1.0594x over previous
//
#include <hip/hip_runtime.h>
#include <hip/hip_bf16.h>

#define NB 4
#define NC 512
#define NN 4096
#define NM 640
#define IB 64            // i-block per iteration
#define NT (NN / IB)     // 64 iterations
#define LOG2E 1.4426950408889634f

typedef __attribute__((ext_vector_type(8))) short bf16x8;
typedef __attribute__((ext_vector_type(4))) float f32x4;

__device__ __forceinline__ f32x4 mfma16(bf16x8 a, bf16x8 b, f32x4 c) {
  return __builtin_amdgcn_mfma_f32_16x16x32_bf16(a, b, c, 0, 0, 0);
}

__device__ __forceinline__ unsigned short f2bf(float f) {
  unsigned int u = __float_as_uint(f);
  u += 0x7fffu + ((u >> 16) & 1u);   // round-to-nearest-even
  return (unsigned short)(u >> 16);
}

typedef const __attribute__((address_space(1))) char gchar_t;
typedef __attribute__((address_space(3))) char lchar_t;

// ---------------- pack weights: W[640][512] bf16 + bias[640] f32 ----------------
__global__ void pack_w(const float* __restrict__ wq, const float* __restrict__ bq,
                       const float* __restrict__ wk, const float* __restrict__ bk,
                       const float* __restrict__ wv, const float* __restrict__ bv,
                       unsigned short* __restrict__ W, float* __restrict__ bias) {
  int idx = blockIdx.x * 256 + threadIdx.x;
  if (idx < NM * NC) {
    int r = idx >> 9, c = idx & (NC - 1);
    float v;
    if (r < 64) v = wq[r * NC + c];
    else if (r < 128) v = wk[(r - 64) * NC + c];
    else v = wv[(r - 128) * NC + c];
    W[idx] = f2bf(v);
  }
  if (idx < NM)
    bias[idx] = (idx < 64) ? bq[idx] : (idx < 128 ? bk[idx - 64] : bv[idx - 128]);
}

// ---------------- transpose + convert: x[b][c][n] f32 -> XT[b][n][c] bf16 ----------------
// v2: float4 loads (16B/lane), b64-packed stores (8B/lane, 4 c per store).
__global__ void xpose(const float* __restrict__ x, unsigned short* __restrict__ XT) {
  __shared__ float t[64][65];
  int b = blockIdx.z;
  int c0 = blockIdx.y * 64, n0 = blockIdx.x * 64;
  int tid = threadIdx.x;        // 256
  int lr = tid >> 4;            // 0..15
  int lc4 = (tid & 15) * 4;     // 0..60
  const float* xb = x + (size_t)b * NC * NN;
#pragma unroll
  for (int i = 0; i < 4; ++i) {
    int c = i * 16 + lr;
    float4 v = *reinterpret_cast<const float4*>(xb + (size_t)(c0 + c) * NN + n0 + lc4);
    t[c][lc4 + 0] = v.x; t[c][lc4 + 1] = v.y; t[c][lc4 + 2] = v.z; t[c][lc4 + 3] = v.w;
  }
  __syncthreads();
  unsigned short* xtb = XT + (size_t)b * NN * NC;
#pragma unroll
  for (int i = 0; i < 4; ++i) {
    int n = i * 16 + lr;
    union { unsigned short h[4]; unsigned long long u; } pk;
#pragma unroll
    for (int e = 0; e < 4; ++e) pk.h[e] = f2bf(t[lc4 + e][n]);
    *reinterpret_cast<unsigned long long*>(xtb + (size_t)(n0 + n) * NC + c0 + lc4) = pk.u;
  }
}

// ---------------- QKV projection GEMM (NT): C[m][n] = sum_k W[m][k]*XT[n][k] ----------------
__global__ __launch_bounds__(512) void gemm_qkv(
    const unsigned short* __restrict__ W, const float* __restrict__ bias,
    const unsigned short* __restrict__ XT,
    unsigned short* __restrict__ QT, unsigned short* __restrict__ KT,
    unsigned short* __restrict__ V) {
  int b = blockIdx.z;
  int m0 = blockIdx.y * 80;
  int wave = threadIdx.x >> 6, lane = threadIdx.x & 63;
  int nw = blockIdx.x * 512 + wave * 64;
  int lcol = lane & 15, lkg = lane >> 4;
  const unsigned short* xtb = XT + (size_t)b * NN * NC;
  f32x4 acc[5][4] = {};
  for (int k0 = 0; k0 < NC; k0 += 32) {
    int ko = k0 + lkg * 8;
    bf16x8 afr[5], bfr[4];
#pragma unroll
    for (int i = 0; i < 5; ++i)
      afr[i] = *reinterpret_cast<const bf16x8*>(W + (size_t)(m0 + 16 * i + lcol) * NC + ko);
#pragma unroll
    for (int j = 0; j < 4; ++j)
      bfr[j] = *reinterpret_cast<const bf16x8*>(xtb + (size_t)(nw + 16 * j + lcol) * NC + ko);
#pragma unroll
    for (int i = 0; i < 5; ++i)
#pragma unroll
      for (int j = 0; j < 4; ++j)
        acc[i][j] = mfma16(afr[i], bfr[j], acc[i][j]);
  }
  int rbase = lkg * 4;
#pragma unroll
  for (int i = 0; i < 5; ++i) {
    int mrow = m0 + 16 * i;
    if (mrow < 128) {
      bool isq = mrow < 64;
      unsigned short* T = isq ? (QT + (size_t)b * NN * 64) : (KT + (size_t)b * NN * 64);
      int mb = mrow & 63;
      float sc = isq ? LOG2E : 1.0f;
#pragma unroll
      for (int j = 0; j < 4; ++j) {
        int n = nw + 16 * j + lcol;
        union { unsigned short h[4]; unsigned long long u; } pk;
#pragma unroll
        for (int r = 0; r < 4; ++r)
          pk.h[r] = f2bf((acc[i][j][r] + bias[mrow + rbase + r]) * sc);
        *reinterpret_cast<unsigned long long*>(T + (size_t)n * 64 + mb + rbase) = pk.u;
      }
    } else {
      unsigned short* vb = V + (size_t)b * NC * NN;
#pragma unroll
      for (int r = 0; r < 4; ++r) {
        int m = mrow + rbase + r;
        float bs = bias[m];
        int c = m - 128;
#pragma unroll
        for (int j = 0; j < 4; ++j) {
          int n = nw + 16 * j + lcol;
          vb[(size_t)c * NN + n] = f2bf(acc[i][j][r] + bs);
        }
      }
    }
  }
}

// ---------------- fused attention PV (R12 structure, hoisted LDS addressing) --------
// grid 256 = (b XCD-pair, jb), 512 threads, 8 waves. Wave w owns c rows [64w,64w+64).
// All P/V LDS read offsets decompose into loop-invariant lane bases + compile-time
// immediates (XOR masks depend only on lcol&7; addend bit-ranges disjoint).
__global__ __launch_bounds__(512, 2) void attn_pv(
    const unsigned short* __restrict__ QT, const unsigned short* __restrict__ KT,
    const unsigned short* __restrict__ V, const float* __restrict__ x,
    const float* __restrict__ gamma, float* __restrict__ out) {
  int bid = blockIdx.x;
  int b = (bid & 7) >> 1;
  int jb = ((bid >> 3) << 1) | (bid & 1);
  int j0 = jb * 64;
  int wave = threadIdx.x >> 6, lane = threadIdx.x & 63;
  int lcol = lane & 15, lkg = lane >> 4;
  int sw = wave >> 1;    // i-strip 0..3
  int fnh = wave & 1;    // fn half: this wave computes fn = 2*fnh + {0,1}

  __shared__ __align__(16) unsigned short vlds[2][512 * IB];  // 128 KB, V dbuf
  __shared__ __align__(16) unsigned short plds[2][64 * IB];   //  16 KB, P^T dbuf
  __shared__ float sml[4][16][4];                             //   1 KB, L cross-wave

  const unsigned short* qt = QT + (size_t)b * NN * 64;
  const unsigned short* kt = KT + (size_t)b * NN * 64;
  const unsigned short* vp = V + (size_t)b * NC * NN;

  // staging geometry: lane -> (row within 8-row group, swizzled 16B unit)
  const int lrow = lane >> 3;                       // 0..7
  const int lswz = ((lane & 7) ^ lrow) << 3;        // source elem offset (unit ^ row&7)
  lchar_t* vbase = (lchar_t*)vlds;

  auto stage = [&](int itv, int buf) {
    int i0 = (itv & (NT - 1)) * IB;
    lchar_t* lb = vbase + (size_t)buf * (512 * IB * 2) + wave * (64 * IB * 2);
#pragma unroll
    for (int q = 0; q < 8; ++q) {
      const unsigned short* gp = vp + (size_t)(wave * 64 + q * 8 + lrow) * NN + i0 + lswz;
      __builtin_amdgcn_global_load_lds((gchar_t*)gp, lb + q * 1024, 16, 0, 0);
    }
  };

  // K fragments for this wave's fn pair
  bf16x8 kfr[2][2];
#pragma unroll
  for (int f = 0; f < 2; ++f) {
    int fn = 2 * fnh + f;
#pragma unroll
    for (int ks = 0; ks < 2; ++ks)
      kfr[f][ks] = *reinterpret_cast<const bf16x8*>(
          kt + (size_t)(j0 + 16 * fn + lcol) * 64 + ks * 32 + lkg * 8);
  }

  f32x4 oacc[4][4] = {};  // [cm][fn]
  float l_loc[2] = {0.f, 0.f};

  // ---- loop-invariant LDS byte offsets ----
  // P write: (j*128 + sw*32 + lkg*8) ^ ((j&7)<<4), j = 16*(2fnh+f) + lcol
  const int jw0 = 16 * (2 * fnh) + lcol, jw1 = jw0 + 16;
  const int pwoff0 = (jw0 * 128 + sw * 32 + lkg * 8) ^ ((jw0 & 7) << 4);
  const int pwoff1 = (jw1 * 128 + sw * 32 + lkg * 8) ^ ((jw1 & 7) << 4);
  // P read: (j*128 + ks*64 + lkg*16)^((lcol&7)<<4) = pk{ks} + fn*2048
  const int pxm = (lcol & 7) << 4;
  const int pk0 = lcol * 128 + ((lkg * 16) ^ (pxm & 0x30)) + (pxm & 0x40);
  const int pk1 = pk0 ^ 64;
  // V read: (64w+16cm+lcol)*128 + ((ks*4+lkg)^(lcol&7))*16 = vk{ks} + cm*2048
  const int vk0 = wave * 8192 + lcol * 128 + ((lkg ^ (lcol & 7)) * 16);
  const int vk1 = vk0 ^ 64;

  const char* Pb[2] = {(const char*)plds, (const char*)plds + 64 * IB * 2};
  const char* Vbs[2] = {(const char*)vlds, (const char*)vlds + 512 * IB * 2};

  // prologue: stage V(0), load Q(0)
  stage(0, 0);
  bf16x8 qA[2], qB[2];
  {
    int row = sw * 16 + lcol;
    qA[0] = *reinterpret_cast<const bf16x8*>(qt + (size_t)row * 64 + lkg * 8);
    qA[1] = *reinterpret_cast<const bf16x8*>(qt + (size_t)row * 64 + 32 + lkg * 8);
  }

#define PV_ITER(IT, QC, QN, BUF)                                                  \
  {                                                                               \
    const int it_ = (IT);                                                         \
    stage(it_ + 1, (BUF) ^ 1);                                                    \
    f32x4 s[2] = {};                                                              \
    _Pragma("unroll") for (int ks = 0; ks < 2; ++ks)                              \
      _Pragma("unroll") for (int f = 0; f < 2; ++f)                               \
        s[f] = mfma16(QC[ks], kfr[f][ks], s[f]);                                  \
    {                                                                             \
      int row = ((it_ + 1) & (NT - 1)) * IB + sw * 16 + lcol;                     \
      QN[0] = *reinterpret_cast<const bf16x8*>(qt + (size_t)row * 64 + lkg * 8);  \
      QN[1] = *reinterpret_cast<const bf16x8*>(qt + (size_t)row * 64 + 32 + lkg * 8); \
    }                                                                             \
    char* pb = (char*)Pb[BUF];                                                    \
    {                                                                             \
      float p0 = exp2f(s[0][0]), p1 = exp2f(s[0][1]);                             \
      float p2 = exp2f(s[0][2]), p3 = exp2f(s[0][3]);                             \
      l_loc[0] += (p0 + p1) + (p2 + p3);                                          \
      union { unsigned short h[4]; unsigned long long u; } pk;                    \
      pk.h[0] = f2bf(p0); pk.h[1] = f2bf(p1);                                     \
      pk.h[2] = f2bf(p2); pk.h[3] = f2bf(p3);                                     \
      *reinterpret_cast<unsigned long long*>(pb + pwoff0) = pk.u;                 \
    }                                                                             \
    {                                                                             \
      float p0 = exp2f(s[1][0]), p1 = exp2f(s[1][1]);                             \
      float p2 = exp2f(s[1][2]), p3 = exp2f(s[1][3]);                             \
      l_loc[1] += (p0 + p1) + (p2 + p3);                                          \
      union { unsigned short h[4]; unsigned long long u; } pk;                    \
      pk.h[0] = f2bf(p0); pk.h[1] = f2bf(p1);                                     \
      pk.h[2] = f2bf(p2); pk.h[3] = f2bf(p3);                                     \
      *reinterpret_cast<unsigned long long*>(pb + pwoff1) = pk.u;                 \
    }                                                                             \
    asm volatile("s_waitcnt vmcnt(10) lgkmcnt(0)" ::: "memory");                  \
    __builtin_amdgcn_s_barrier();                                                 \
    asm volatile("" ::: "memory");                                                \
    const char* vbw = Vbs[BUF];                                                   \
    __builtin_amdgcn_s_setprio(1);                                                \
    _Pragma("unroll") for (int ks = 0; ks < 2; ++ks) {                            \
      const int pko = ks ? pk1 : pk0;                                             \
      const int vko = ks ? vk1 : vk0;                                             \
      bf16x8 pfr[4];                                                              \
      _Pragma("unroll") for (int fn = 0; fn < 4; ++fn)                            \
        pfr[fn] = *reinterpret_cast<const bf16x8*>(pb + pko + fn * 2048);         \
      _Pragma("unroll") for (int cm = 0; cm < 4; ++cm) {                          \
        bf16x8 vfr = *reinterpret_cast<const bf16x8*>(vbw + vko + cm * 2048);     \
        _Pragma("unroll") for (int fn = 0; fn < 4; ++fn)                          \
          oacc[cm][fn] = mfma16(vfr, pfr[fn], oacc[cm][fn]);                      \
      }                                                                           \
    }                                                                             \
    __builtin_amdgcn_s_setprio(0);                                                \
  }

  for (int it2 = 0; it2 < NT; it2 += 2) {
    PV_ITER(it2 + 0, qA, qB, 0);
    PV_ITER(it2 + 1, qB, qA, 1);
  }
#undef PV_ITER

  // ---- L cross-wave reduce ----
#pragma unroll
  for (int f = 0; f < 2; ++f) {
    l_loc[f] += __shfl_xor(l_loc[f], 16);
    l_loc[f] += __shfl_xor(l_loc[f], 32);
  }
  if (lane < 16) {
#pragma unroll
    for (int f = 0; f < 2; ++f) sml[2 * fnh + f][lane][sw] = l_loc[f];
  }
  __syncthreads();
  float lj[4];
#pragma unroll
  for (int fn = 0; fn < 4; ++fn) {
    const float* p = sml[fn][lcol];
    lj[fn] = (p[0] + p[1]) + (p[2] + p[3]);
  }

  // ---- epilogue: out = gamma * O/l + x ----
  float g = gamma[0];
  const float* xb = x + (size_t)b * NC * NN;
  float* ob = out + (size_t)b * NC * NN;
#pragma unroll
  for (int fn = 0; fn < 4; ++fn) {
    float sc = g / lj[fn];
    int j = j0 + 16 * fn + lcol;
#pragma unroll
    for (int cm = 0; cm < 4; ++cm) {
      int c = 64 * wave + 16 * cm + lkg * 4;
#pragma unroll
      for (int r = 0; r < 4; ++r) {
        size_t idx = (size_t)(c + r) * NN + j;
        ob[idx] = oacc[cm][fn][r] * sc + xb[idx];
      }
    }
  }
}

extern "C" void kernel_launch(void* const* d_in, const int* in_sizes, int n_in,
                              void* d_out, int out_size, void* d_ws, size_t ws_size,
                              hipStream_t stream) {
  const float* x  = (const float*)d_in[0];
  const float* wq = (const float*)d_in[1];
  const float* bq = (const float*)d_in[2];
  const float* wk = (const float*)d_in[3];
  const float* bk = (const float*)d_in[4];
  const float* wv = (const float*)d_in[5];
  const float* bv = (const float*)d_in[6];
  const float* gm = (const float*)d_in[7];
  float* out = (float*)d_out;

  char* ws = (char*)d_ws;
  unsigned short* XT = (unsigned short*)(ws);                             // 16 MB
  unsigned short* Vb = (unsigned short*)(ws + (size_t)16 * 1024 * 1024);  // 16 MB
  unsigned short* QT = (unsigned short*)(ws + (size_t)32 * 1024 * 1024);  // 2 MB
  unsigned short* KT = (unsigned short*)(ws + (size_t)34 * 1024 * 1024);  // 2 MB
  unsigned short* Wp = (unsigned short*)(ws + (size_t)36 * 1024 * 1024);  // 640 KB
  float* biasp = (float*)(ws + (size_t)36 * 1024 * 1024 + 704 * 1024);    // 2.5 KB

  pack_w<<<(NM * NC + 255) / 256, 256, 0, stream>>>(wq, bq, wk, bk, wv, bv, Wp, biasp);
  xpose<<<dim3(NN / 64, NC / 64, NB), 256, 0, stream>>>(x, XT);
  gemm_qkv<<<dim3(NN / 512, NM / 80, NB), 512, 0, stream>>>(Wp, biasp, XT, QT, KT, Vb);
  attn_pv<<<256, 512, 0, stream>>>(QT, KT, Vb, x, gm, out);
}